// Round 4
// baseline (385.749 us; speedup 1.0000x reference)
//
#include <hip/hip_runtime.h>
#include <math.h>

// ManifoldAlignmentLoss: B=256, D=512, N=50000, A=8, K=5
// R8 = R5's proven structures, edges shaved: 3 launches.
//   prep_lite: zinv[b] only (no z_norm round-trip) + zero state.
//   match:     R5 LDS-compaction flat pair list (one global atomic/block),
//              + per-b expected[] counts with STAGGERED b-traversal
//              (R7 lesson: lockstep b-sweep hot-lines the counter atomics).
//   dot_topk:  R5 grid-stride 16-lane-group dot (9 blocks/CU), sims written
//              with device-scope stores; per-b done-counter trick fires an
//              inline 16-lane top-5 on the group finishing b's last pair.
// Accounting: ~124us big fills + ~25-30us tiny harness resets are fixed;
// our controllable slice is ~26us with a ~15us floor. R7's regression was
// lockstep atomics + 1-block/CU imbalance, not launch count.

constexpr int D = 512;
constexpr int A = 8;
constexpr int K_NEI = 5;
constexpr int SLOTS = 512;        // per-b sim capacity (mean ~130, +33 sigma)
constexpr int CSTRIDE = 16;       // counter padding: 64B per counter line
constexpr int PAIR_CAP = 65536;   // flat pair list capacity (mean ~33K)
constexpr int LDS_PAIR_CAP = 1024;
constexpr int DOT_BLOCKS = 2304;  // x16 groups = 36864 >= np

__device__ __forceinline__ unsigned pack_attrs(const int4 x, const int4 y) {
    return  ((unsigned)x.x & 0xFu)        | (((unsigned)x.y & 0xFu) << 4)
          | (((unsigned)x.z & 0xFu) << 8)  | (((unsigned)x.w & 0xFu) << 12)
          | (((unsigned)y.x & 0xFu) << 16) | (((unsigned)y.y & 0xFu) << 20)
          | (((unsigned)y.z & 0xFu) << 24) | (((unsigned)y.w & 0xFu) << 28);
}

// ---------------- prep_lite: zinv[b], zero counters/expected/done/out ------
// grid = B blocks x 64 threads
__global__ __launch_bounds__(64) void prep_kernel(
    const float* __restrict__ z, float* __restrict__ zinv,
    int* __restrict__ counters, int* __restrict__ expected,
    int* __restrict__ done, int* __restrict__ npairs, float* __restrict__ out)
{
    const int b = blockIdx.x;
    const int lane = threadIdx.x;
    const float4* zrow = (const float4*)(z + (size_t)b * D);
    const float4 v0 = zrow[lane * 2 + 0];
    const float4 v1 = zrow[lane * 2 + 1];
    float ss = v0.x*v0.x + v0.y*v0.y + v0.z*v0.z + v0.w*v0.w
             + v1.x*v1.x + v1.y*v1.y + v1.z*v1.z + v1.w*v1.w;
    #pragma unroll
    for (int m = 1; m < 64; m <<= 1) ss += __shfl_xor(ss, m, 64);
    if (lane == 0) {
        zinv[b] = 1.0f / fmaxf(sqrtf(ss), 1e-12f);
        counters[b * CSTRIDE] = 0;
        expected[b * CSTRIDE] = 0;
        done[b * CSTRIDE]     = 0;
        if (b == 0) { *npairs = 0; out[0] = 0.0f; }
    }
}

// ---------------- match: LDS compaction -> flat pairs; staggered expected --
// grid = ceil(N/256) blocks x 256 threads
__global__ __launch_bounds__(256) void match_kernel(
    const int* __restrict__ trattr, const int* __restrict__ tattr,
    unsigned* __restrict__ pairs, int* __restrict__ npairs,
    int* __restrict__ expected, int N)
{
    __shared__ unsigned s_tp[256];
    __shared__ unsigned s_pairs[LDS_PAIR_CAP];
    __shared__ int s_cnt, s_base;

    const int tid = threadIdx.x;
    const int n = blockIdx.x * 256 + tid;

    {   // pack all 256 target patterns directly from tattr (8KB, L2-resident)
        const int4* t4 = (const int4*)(tattr + (size_t)tid * A);
        s_tp[tid] = pack_attrs(t4[0], t4[1]);
    }
    if (tid == 0) s_cnt = 0;
    __syncthreads();

    if (n < N) {
        const int4* a4 = (const int4*)(trattr + (size_t)n * A);
        const unsigned p = pack_attrs(a4[0], a4[1]);
        const uint4* tp4 = (const uint4*)s_tp;
        const int start = n & 63;   // stagger: decorrelate expected[] atomics
        #pragma unroll 4
        for (int bqi = 0; bqi < 64; bqi++) {
            const int bq = (start + bqi) & 63;
            const uint4 t = tp4[bq];
            #pragma unroll
            for (int j = 0; j < 4; j++) {
                const unsigned tv = (j == 0) ? t.x : (j == 1) ? t.y : (j == 2) ? t.z : t.w;
                const unsigned yv = p ^ tv;
                // hi bit of each nibble set iff nibble nonzero
                const unsigned nzhi = ((((yv & 0x77777777u) + 0x77777777u) | yv) & 0x88888888u);
                if (__popc(nzhi) <= 1) {   // >= A-1 matching attrs
                    const int b = bq * 4 + j;
                    atomicAdd(&expected[b * CSTRIDE], 1);
                    const int idx = atomicAdd(&s_cnt, 1);
                    if (idx < LDS_PAIR_CAP)
                        s_pairs[idx] = ((unsigned)n << 8) | (unsigned)b;
                }
            }
        }
    }
    __syncthreads();
    const int cnt = min(s_cnt, LDS_PAIR_CAP);
    if (tid == 0) s_base = atomicAdd(npairs, cnt);
    __syncthreads();
    const int base = s_base;
    for (int i = tid; i < cnt; i += 256)
        if (base + i < PAIR_CAP) pairs[base + i] = s_pairs[i];
}

// ---------------- dot + inline per-b topk (done-counter trick) -------------
// grid = DOT_BLOCKS x 256 threads (16 groups/block, grid-stride over pairs)
__global__ __launch_bounds__(256) void dot_topk_kernel(
    const float* __restrict__ train, const float* __restrict__ z,
    const float* __restrict__ zinv, const unsigned* __restrict__ pairs,
    const int* __restrict__ npairs, int* __restrict__ counters,
    const int* __restrict__ expected, int* __restrict__ done,
    float* __restrict__ simbuf, float* __restrict__ out, int Bt)
{
    const int lane = threadIdx.x & 15;                    // lane within group
    const int g0 = blockIdx.x * 16 + (threadIdx.x >> 4);  // group id
    const int ngroups = DOT_BLOCKS * 16;
    const int np = min(*npairs, PAIR_CAP);
    const int lw = threadIdx.x & 63;                      // lane within wave
    const int gbase = lw & ~15;                           // group base lane in wave
    const unsigned long long gmask = 0xFFFFull << gbase;

    for (int i = g0; i < np; i += ngroups) {
        const unsigned pr = pairs[i];
        const int n = (int)(pr >> 8);
        const int b = (int)(pr & 255u);
        const float4* __restrict__ row4 = (const float4*)(train + (size_t)n * D);
        const float4* __restrict__ z4   = (const float4*)(z     + (size_t)b * D);

        float4 r[8], q[8];
        #pragma unroll
        for (int j = 0; j < 8; j++) r[j] = row4[j * 16 + lane];
        #pragma unroll
        for (int j = 0; j < 8; j++) q[j] = z4[j * 16 + lane];
        const float zi = zinv[b];
        #pragma unroll
        for (int j = 0; j < 8; j++) {  // identical rounding to R5's prep
            q[j].x *= zi; q[j].y *= zi; q[j].z *= zi; q[j].w *= zi;
        }

        float ss = 0.0f, dd = 0.0f;
        #pragma unroll
        for (int j = 0; j < 8; j++) {
            ss += r[j].x*r[j].x + r[j].y*r[j].y + r[j].z*r[j].z + r[j].w*r[j].w;
            dd += r[j].x*q[j].x + r[j].y*q[j].y + r[j].z*q[j].z + r[j].w*q[j].w;
        }
        #pragma unroll
        for (int mm = 1; mm < 16; mm <<= 1) {
            ss += __shfl_xor(ss, mm, 64);
            dd += __shfl_xor(dd, mm, 64);
        }

        int lastf = 0;
        if (lane == 0) {
            const float sim = dd / fmaxf(sqrtf(ss), 1e-12f);
            const int idx = atomicAdd(&counters[b * CSTRIDE], 1);
            if (idx < SLOTS)
                __hip_atomic_store(&simbuf[(size_t)b * SLOTS + idx], sim,
                                   __ATOMIC_RELAXED, __HIP_MEMORY_SCOPE_AGENT);
            const int d = __hip_atomic_fetch_add(&done[b * CSTRIDE], 1,
                                   __ATOMIC_ACQ_REL, __HIP_MEMORY_SCOPE_AGENT);
            lastf = (d == expected[b * CSTRIDE] - 1);
        }
        lastf = __shfl(lastf, gbase, 64);   // broadcast within 16-lane group

        if (lastf) {
            // this group completed b's last pair: all sims for b are stored
            __threadfence();
            const int totc = expected[b * CSTRIDE];
            const int m = min(totc, SLOTS);
            const float* buf = simbuf + (size_t)b * SLOTS;

            float v[32];
            #pragma unroll
            for (int k = 0; k < 32; k++) {
                const int s_i = k * 16 + lane;
                v[k] = (s_i < m)
                     ? __hip_atomic_load(&buf[s_i], __ATOMIC_RELAXED,
                                         __HIP_MEMORY_SCOPE_AGENT)
                     : -1e30f;
            }

            float s = 0.0f;
            #pragma unroll
            for (int r5 = 0; r5 < K_NEI; r5++) {
                float best = v[0];
                #pragma unroll
                for (int k = 1; k < 32; k++) best = fmaxf(best, v[k]);
                float M = best;
                #pragma unroll
                for (int mm = 1; mm < 16; mm <<= 1) M = fmaxf(M, __shfl_xor(M, mm, 64));
                s += fmaxf(M, 0.0f);  // N-cnt exact zeros dominate negatives
                const unsigned long long bal = __ballot(best == M) & gmask;
                const int first = __ffsll(bal) - 1;
                if (lw == first) {
                    #pragma unroll
                    for (int k = 0; k < 32; k++) {
                        if (v[k] == M) { v[k] = -1e30f; break; }
                    }
                }
            }
            if (lane == 0) {
                const float contrib = (totc >= K_NEI) ? (1.0f - s * (1.0f / K_NEI)) : 0.0f;
                atomicAdd(out, contrib / (float)Bt);
            }
        }
    }
}

extern "C" void kernel_launch(void* const* d_in, const int* in_sizes, int n_in,
                              void* d_out, int out_size, void* d_ws, size_t ws_size,
                              hipStream_t stream)
{
    const float* z      = (const float*)d_in[0];   // [B, D] f32
    const int*   tattr  = (const int*)d_in[1];     // [B, A] i32
    const float* train  = (const float*)d_in[2];   // [N, D] f32
    const int*   trattr = (const int*)d_in[3];     // [N, A] i32
    float* out = (float*)d_out;

    const int B = in_sizes[0] / D;     // 256
    const int N = in_sizes[2] / D;     // 50000

    // ws layout
    char* ws = (char*)d_ws;
    float*    zinv     = (float*)ws;    ws += (size_t)B * sizeof(float);
    int*      counters = (int*)ws;      ws += (size_t)B * CSTRIDE * sizeof(int);
    int*      expected = (int*)ws;      ws += (size_t)B * CSTRIDE * sizeof(int);
    int*      done     = (int*)ws;      ws += (size_t)B * CSTRIDE * sizeof(int);
    float*    simbuf   = (float*)ws;    ws += (size_t)B * SLOTS * sizeof(float);
    int*      npairs   = (int*)ws;      ws += 64;
    unsigned* pairs    = (unsigned*)ws;

    prep_kernel<<<B, 64, 0, stream>>>(z, zinv, counters, expected, done, npairs, out);
    match_kernel<<<(N + 255) / 256, 256, 0, stream>>>(trattr, tattr, pairs, npairs, expected, N);
    dot_topk_kernel<<<DOT_BLOCKS, 256, 0, stream>>>(train, z, zinv, pairs, npairs,
                                                    counters, expected, done, simbuf, out, B);
}

// Round 5
// 176.903 us; speedup vs baseline: 2.1806x; 2.1806x over previous
//
#include <hip/hip_runtime.h>
#include <math.h>

// ManifoldAlignmentLoss: B=256, D=512, N=50000, A=8, K=5
// R9 = exact revert to R5 (best measured: 175.885us, passed, absmax 0).
// Sparse pair-list strategy: prep -> match (pair compaction) -> dot -> topk.
// Session ledger:
//   R3: fusing match+dot starves grid (196 blocks -> 7% occ). FAILED.
//   R5: 16-lane-group dot, 16 loads/lane MLP, single sweep. 175.9us. BEST.
//   R6: memset+2-kernel fusion -> harness capture death. FAILED.
//   R7: per-b bucket atomics in match (lockstep b-sweep hot-lines) +
//       1-block/CU dot_topk. 186.8us. FAILED.
//   R8: done-counter inline topk + agent-scope atomics -> scratch-capped
//       occupancy (25%), dot 250us. 385.7us. FAILED.
// Accounting: ~123us poison fills + ~25-30us tiny harness resets are fixed;
// our 4 kernels sum to ~20us (dot ~10us at its fetch floor). Headroom <=8us;
// three structural attempts to claim it all regressed. This is the floor.

constexpr int D = 512;
constexpr int A = 8;
constexpr int K_NEI = 5;
constexpr int SLOTS = 512;        // per-b sim bucket capacity (mean ~130)
constexpr int CSTRIDE = 16;       // counter padding: 64B per counter line
constexpr int PAIR_CAP = 65536;   // global pair list capacity (mean ~33K)
constexpr int LDS_PAIR_CAP = 1024;
constexpr int DOT_BLOCKS = 2304;  // x16 groups = 36864 groups >= np (33K mean)

__device__ __forceinline__ float wave_reduce_add(float v) {
    #pragma unroll
    for (int m = 1; m < 64; m <<= 1) v += __shfl_xor(v, m, 64);
    return v;
}

// ---------------- prep: normalize z rows, pack target attrs, zero state ----
// grid = B blocks x 64 threads
__global__ __launch_bounds__(64) void prep_kernel(
    const float* __restrict__ z, const int* __restrict__ tattr,
    float* __restrict__ z_norm, unsigned* __restrict__ tpacked,
    int* __restrict__ counters, int* __restrict__ npairs,
    float* __restrict__ out)
{
    const int b = blockIdx.x;
    const int lane = threadIdx.x;
    const float4* zrow = (const float4*)(z + (size_t)b * D);
    float4 v0 = zrow[lane * 2 + 0];
    float4 v1 = zrow[lane * 2 + 1];
    float ss = v0.x*v0.x + v0.y*v0.y + v0.z*v0.z + v0.w*v0.w
             + v1.x*v1.x + v1.y*v1.y + v1.z*v1.z + v1.w*v1.w;
    ss = wave_reduce_add(ss);
    const float scale = 1.0f / fmaxf(sqrtf(ss), 1e-12f);
    v0.x *= scale; v0.y *= scale; v0.z *= scale; v0.w *= scale;
    v1.x *= scale; v1.y *= scale; v1.z *= scale; v1.w *= scale;
    float4* orow = (float4*)(z_norm + (size_t)b * D);
    orow[lane * 2 + 0] = v0;
    orow[lane * 2 + 1] = v1;
    if (lane == 0) {
        unsigned p = 0;
        #pragma unroll
        for (int a = 0; a < A; a++)
            p |= ((unsigned)tattr[b * A + a] & 0xFu) << (4 * a);
        tpacked[b] = p;
        counters[b * CSTRIDE] = 0;
        if (b == 0) { *npairs = 0; out[0] = 0.0f; }
    }
}

// ---------------- match: one thread per train row, compact pairs ----------
// grid = ceil(N/256) blocks x 256 threads
__global__ __launch_bounds__(256) void match_kernel(
    const int* __restrict__ trattr, const unsigned* __restrict__ tpacked,
    unsigned* __restrict__ pairs, int* __restrict__ npairs, int N)
{
    __shared__ unsigned s_tp[256];
    __shared__ unsigned s_pairs[LDS_PAIR_CAP];
    __shared__ int s_cnt, s_base;

    const int tid = threadIdx.x;
    const int n = blockIdx.x * 256 + tid;
    s_tp[tid] = tpacked[tid];
    if (tid == 0) s_cnt = 0;
    __syncthreads();

    if (n < N) {
        const int4* a4 = (const int4*)(trattr + (size_t)n * A);
        const int4 x = a4[0], y = a4[1];
        const unsigned p =
             ((unsigned)x.x & 0xFu)        | (((unsigned)x.y & 0xFu) << 4)
           | (((unsigned)x.z & 0xFu) << 8)  | (((unsigned)x.w & 0xFu) << 12)
           | (((unsigned)y.x & 0xFu) << 16) | (((unsigned)y.y & 0xFu) << 20)
           | (((unsigned)y.z & 0xFu) << 24) | (((unsigned)y.w & 0xFu) << 28);

        const uint4* tp4 = (const uint4*)s_tp;
        #pragma unroll 4
        for (int bq = 0; bq < 64; bq++) {
            const uint4 t = tp4[bq];
            #pragma unroll
            for (int j = 0; j < 4; j++) {
                const unsigned tv = (j == 0) ? t.x : (j == 1) ? t.y : (j == 2) ? t.z : t.w;
                const unsigned yv = p ^ tv;
                // hi bit of each nibble set iff nibble nonzero
                const unsigned nzhi = ((((yv & 0x77777777u) + 0x77777777u) | yv) & 0x88888888u);
                if (__popc(nzhi) <= 1) {   // >= A-1 matching attrs
                    const int idx = atomicAdd(&s_cnt, 1);
                    if (idx < LDS_PAIR_CAP)
                        s_pairs[idx] = ((unsigned)n << 8) | (unsigned)(bq * 4 + j);
                }
            }
        }
    }
    __syncthreads();
    const int cnt = min(s_cnt, LDS_PAIR_CAP);
    if (tid == 0) s_base = atomicAdd(npairs, cnt);
    __syncthreads();
    const int base = s_base;
    for (int i = tid; i < cnt; i += 256)
        if (base + i < PAIR_CAP) pairs[base + i] = s_pairs[i];
}

// ---------------- dot: one 16-lane group per pair, single sweep -----------
// grid = DOT_BLOCKS x 256 threads (16 groups/block)
__global__ __launch_bounds__(256) void dot_kernel(
    const float* __restrict__ train, const float* __restrict__ z_norm,
    const unsigned* __restrict__ pairs, const int* __restrict__ npairs,
    int* __restrict__ counters, float* __restrict__ simbuf)
{
    const int lane = threadIdx.x & 15;                    // lane within group
    const int g0 = blockIdx.x * 16 + (threadIdx.x >> 4);  // group id
    const int ngroups = DOT_BLOCKS * 16;                  // 36864
    const int np = min(*npairs, PAIR_CAP);

    for (int i = g0; i < np; i += ngroups) {
        const unsigned pr = pairs[i];
        const float4* __restrict__ row4 = (const float4*)(train  + (size_t)(pr >> 8)   * D);
        const float4* __restrict__ zr4  = (const float4*)(z_norm + (size_t)(pr & 255u) * D);

        // 16 independent float4 loads per lane; each instruction is a
        // contiguous 256B segment per group (row4[j*16 + lane]).
        float4 r[8], zz[8];
        #pragma unroll
        for (int j = 0; j < 8; j++) r[j]  = row4[j * 16 + lane];
        #pragma unroll
        for (int j = 0; j < 8; j++) zz[j] = zr4[j * 16 + lane];

        float ss = 0.0f, dd = 0.0f;
        #pragma unroll
        for (int j = 0; j < 8; j++) {
            ss += r[j].x*r[j].x  + r[j].y*r[j].y  + r[j].z*r[j].z  + r[j].w*r[j].w;
            dd += r[j].x*zz[j].x + r[j].y*zz[j].y + r[j].z*zz[j].z + r[j].w*zz[j].w;
        }
        #pragma unroll
        for (int m = 1; m < 16; m <<= 1) {
            ss += __shfl_xor(ss, m, 64);
            dd += __shfl_xor(dd, m, 64);
        }
        if (lane == 0) {
            const int b = (int)(pr & 255u);
            const float sim = dd / fmaxf(sqrtf(ss), 1e-12f);
            const int idx = atomicAdd(&counters[b * CSTRIDE], 1);
            if (idx < SLOTS) simbuf[(size_t)b * SLOTS + idx] = sim;
        }
    }
}

// ---------------- topk: one wave per b, 5x wave-max, atomic into out ------
// grid = 256 blocks x 64 threads
__global__ __launch_bounds__(64) void topk_kernel(
    const int* __restrict__ counters, const float* __restrict__ simbuf,
    float* __restrict__ out, int Bt)
{
    const int b = blockIdx.x;
    const int lane = threadIdx.x;
    const int cnt = counters[b * CSTRIDE];
    const int m = min(cnt, SLOTS);
    const float* buf = simbuf + (size_t)b * SLOTS;

    float v[8];
    #pragma unroll
    for (int k = 0; k < 8; k++) {
        const int i = lane + k * 64;
        v[k] = (i < m) ? buf[i] : -1e30f;
    }

    float s = 0.0f;
    #pragma unroll
    for (int r = 0; r < K_NEI; r++) {
        float best = v[0];
        #pragma unroll
        for (int k = 1; k < 8; k++) best = fmaxf(best, v[k]);
        float M = best;
        #pragma unroll
        for (int mm = 1; mm < 64; mm <<= 1) M = fmaxf(M, __shfl_xor(M, mm, 64));
        s += fmaxf(M, 0.0f);   // N-cnt exact zeros from unmatched entries dominate negatives
        const unsigned long long bal = __ballot(best == M);
        const int first = __ffsll(bal) - 1;
        if (lane == first) {
            if      (v[0] == M) v[0] = -1e30f;
            else if (v[1] == M) v[1] = -1e30f;
            else if (v[2] == M) v[2] = -1e30f;
            else if (v[3] == M) v[3] = -1e30f;
            else if (v[4] == M) v[4] = -1e30f;
            else if (v[5] == M) v[5] = -1e30f;
            else if (v[6] == M) v[6] = -1e30f;
            else                v[7] = -1e30f;
        }
    }

    if (lane == 0) {
        const float contrib = (cnt >= K_NEI) ? (1.0f - s * (1.0f / K_NEI)) : 0.0f;
        atomicAdd(out, contrib / (float)Bt);
    }
}

extern "C" void kernel_launch(void* const* d_in, const int* in_sizes, int n_in,
                              void* d_out, int out_size, void* d_ws, size_t ws_size,
                              hipStream_t stream)
{
    const float* z      = (const float*)d_in[0];   // [B, D] f32
    const int*   tattr  = (const int*)d_in[1];     // [B, A] i32
    const float* train  = (const float*)d_in[2];   // [N, D] f32
    const int*   trattr = (const int*)d_in[3];     // [N, A] i32
    float* out = (float*)d_out;

    const int B = in_sizes[0] / D;     // 256
    const int N = in_sizes[2] / D;     // 50000

    // ws layout
    char* ws = (char*)d_ws;
    float*    z_norm   = (float*)ws;    ws += (size_t)B * D * sizeof(float);
    unsigned* tpacked  = (unsigned*)ws; ws += (size_t)B * sizeof(unsigned);
    int*      counters = (int*)ws;      ws += (size_t)B * CSTRIDE * sizeof(int);
    float*    simbuf   = (float*)ws;    ws += (size_t)B * SLOTS * sizeof(float);
    int*      npairs   = (int*)ws;      ws += 64;
    unsigned* pairs    = (unsigned*)ws;

    prep_kernel<<<B, 64, 0, stream>>>(z, tattr, z_norm, tpacked, counters, npairs, out);
    match_kernel<<<(N + 255) / 256, 256, 0, stream>>>(trattr, tpacked, pairs, npairs, N);
    dot_kernel<<<DOT_BLOCKS, 256, 0, stream>>>(train, z_norm, pairs, npairs, counters, simbuf);
    topk_kernel<<<B, 64, 0, stream>>>(counters, simbuf, out, B);
}